// Round 3
// baseline (701.000 us; speedup 1.0000x reference)
//
#include <hip/hip_runtime.h>

// B=4, M=4096, N2=8192 (k/v split at 4096), D=128, f32 in/out.
// out = rl * (e^(s*scale) @ V) + mask @ V   (fixed-max softmax; rl = 1/rowsum)
// nsplit=4 over n; per-block partials (bf16 pair) + rowsum (f32) -> combine kernel.
// ws (ushort): q[4][4096][128] | k[4][4096][128] | vT[4][128][4096] | Wq_bf | Wkv_bf
//              | part u32 [4ns][4b][4096][128] (32MB) | rsum f32 [4ns][4b][4096]

typedef __attribute__((ext_vector_type(8))) short bf16x8;
typedef __attribute__((ext_vector_type(4))) float f32x4;

static constexpr float kSc = 0.08838834764831845f * 1.4426950408889634f; // 1/sqrt(128)*log2e

__device__ __forceinline__ unsigned short f2bf(float f) {
  unsigned int u = __float_as_uint(f);
  u = (u + 0x7fffu + ((u >> 16) & 1u)) >> 16;   // RNE
  return (unsigned short)u;
}

__device__ __forceinline__ float fast_exp2(float v) {
#if __has_builtin(__builtin_amdgcn_exp2f)
  return __builtin_amdgcn_exp2f(v);
#else
  return exp2f(v);
#endif
}

// ---------------- kernel 0: W f32 -> bf16 ----------------------------------
__global__ __launch_bounds__(256) void wcvt_kernel(
    const float* __restrict__ Wq, const float* __restrict__ Wkv,
    unsigned short* __restrict__ wqb, unsigned short* __restrict__ wkb)
{
  const int t = blockIdx.x * 256 + threadIdx.x;
  #pragma unroll
  for (int s = 0; s < 2; s++) {
    const float* src = s ? Wkv : Wq;
    unsigned short* dst = s ? wkb : wqb;
    float4 a = ((const float4*)src)[t * 2], b = ((const float4*)src)[t * 2 + 1];
    ((ushort4*)dst)[t * 2]     = make_ushort4(f2bf(a.x), f2bf(a.y), f2bf(a.z), f2bf(a.w));
    ((ushort4*)dst)[t * 2 + 1] = make_ushort4(f2bf(b.x), f2bf(b.y), f2bf(b.z), f2bf(b.w));
  }
}

// ---------------- kernel 1: projections -------------------------------------
__global__ __launch_bounds__(256) void proj_kernel(
    const float* __restrict__ x, const float* __restrict__ cond,
    const unsigned short* __restrict__ wqb, const unsigned short* __restrict__ wkb,
    unsigned short* __restrict__ qws, unsigned short* __restrict__ kws,
    unsigned short* __restrict__ vTws)
{
  __shared__ __align__(16) unsigned short lds[128 * 88];
  const int bid = blockIdx.x, tid = threadIdx.x;
  const int wave = tid >> 6, l = tid & 63, l15 = l & 15, l4 = l >> 4;

  const float* src; const unsigned short* W;
  int mode; size_t row0;
  if (bid < 256) { mode = 0; src = x; W = wqb; row0 = (size_t)bid * 64; }
  else { row0 = (size_t)(bid - 256) * 64; src = cond; W = wkb;
         mode = ((int)(row0 & 8191) < 4096) ? 1 : 2; }
  const size_t rw = row0 + wave * 16;

  f32x4 ar[8];
  const float* rp = src + (rw + l15) * 128 + l4 * 8;
  #pragma unroll
  for (int ks = 0; ks < 4; ks++) {
    ar[2 * ks]     = *(const f32x4*)(rp + ks * 32);
    ar[2 * ks + 1] = *(const f32x4*)(rp + ks * 32 + 4);
  }
  bf16x8 af[4];
  #pragma unroll
  for (int ks = 0; ks < 4; ks++) {
    bf16x8 a;
    #pragma unroll
    for (int j = 0; j < 4; j++) {
      a[j]     = (short)f2bf(ar[2 * ks][j]);
      a[4 + j] = (short)f2bf(ar[2 * ks + 1][j]);
    }
    af[ks] = a;
  }

  f32x4 acc[8];
  #pragma unroll
  for (int d = 0; d < 8; d++) acc[d] = (f32x4){0.f, 0.f, 0.f, 0.f};

  const unsigned short* wp = W + l15 * 128 + l4 * 8;
  #pragma unroll
  for (int d = 0; d < 8; d++)
    #pragma unroll
    for (int ks = 0; ks < 4; ks++) {
      bf16x8 wf = *(const bf16x8*)(wp + d * 16 * 128 + ks * 32);
      acc[d] = __builtin_amdgcn_mfma_f32_16x16x32_bf16(af[ks], wf, acc[d], 0, 0, 0);
    }

  if (mode < 2) {
    #pragma unroll
    for (int d = 0; d < 8; d++)
      #pragma unroll
      for (int r = 0; r < 4; r++)
        lds[(wave * 16 + l4 * 4 + r) * 136 + d * 16 + l15] = f2bf(acc[d][r]);
    __syncthreads();
    size_t obase; unsigned short* outp;
    if (mode == 0) { outp = qws; obase = row0; }
    else { outp = kws; obase = (row0 >> 13) * 4096 + (row0 & 8191); }
    const int row = tid >> 2, ch = (tid & 3) * 32;
    const unsigned short* sp = lds + row * 136 + ch;
    unsigned short* gp = outp + (obase + row) * 128 + ch;
    #pragma unroll
    for (int i = 0; i < 4; i++)
      *(int4*)(gp + i * 8) = *(const int4*)(sp + i * 8);
  } else {
    #pragma unroll
    for (int d = 0; d < 8; d++)
      #pragma unroll
      for (int r = 0; r < 4; r++)
        lds[(d * 16 + l15) * 88 + wave * 16 + l4 * 4 + r] = f2bf(acc[d][r]);
    __syncthreads();
    const size_t b = row0 >> 13;
    const int n0 = (int)(row0 & 8191) - 4096;
    const int dd = tid >> 1, half = tid & 1;
    const unsigned short* sp = lds + dd * 88 + half * 32;
    unsigned short* gp = vTws + ((size_t)b * 128 + dd) * 4096 + n0 + half * 32;
    #pragma unroll
    for (int i = 0; i < 4; i++)
      *(int4*)(gp + i * 8) = *(const int4*)(sp + i * 8);
  }
}

// ---------------- kernel 2: attention partials ------------------------------
// 1024 blocks x 256 thr (4 waves = 4 rowgroups of 16). Block: (b, ns, m-tile 64).
// n-range [ns*1024, +1024) in 16 tiles of 64. No barriers in loop; frags direct
// from L1/L2; only P1 redistribution goes through (wave-private, swizzled) LDS.
__global__ __launch_bounds__(256, 3) void attn_kernel(
    const unsigned short* __restrict__ qws,
    const unsigned short* __restrict__ kws,
    const unsigned short* __restrict__ vTws,
    const float* __restrict__ mask,
    unsigned int* __restrict__ part,
    float* __restrict__ rsumws)
{
  __shared__ __align__(16) unsigned short pbuf[4][16 * 64];  // 8KB, swizzled units

  const int bid = blockIdx.x;
  const int c = bid & 15, grp = bid >> 4;      // c mod 8 = XCD -> (b,ns) L2-pinned
  const int b = c >> 2, ns = c & 3;
  const int m0 = grp * 64;
  const int tid = threadIdx.x, w = tid >> 6, l = tid & 63;
  const int l15 = l & 15, l4 = l >> 4, l7 = l15 & 7;
  const int nbase = ns * 1024;

  bf16x8 qf[4];
  {
    const unsigned short* qp = qws + ((size_t)b * 4096 + m0 + w * 16 + l15) * 128 + l4 * 8;
    #pragma unroll
    for (int ks = 0; ks < 4; ks++) qf[ks] = *(const bf16x8*)(qp + ks * 32);
  }

  f32x4 acc1[8], acc2[8];
  #pragma unroll
  for (int d = 0; d < 8; d++) { acc1[d] = (f32x4){0,0,0,0}; acc2[d] = (f32x4){0,0,0,0}; }
  float lsum[4] = {0.f, 0.f, 0.f, 0.f};

  const unsigned short* kb = kws  + ((size_t)b * 4096 + nbase + l15) * 128 + l4 * 8;
  const unsigned short* vb = vTws + ((size_t)b * 128 + l15) * 4096 + nbase + l4 * 8;
  const float* mrow = mask + ((size_t)(b * 4096 + m0 + w * 16 + l15)) * 4096 + nbase + l4 * 8;
  unsigned short* pb = &pbuf[w][0];

  for (int nt = 0; nt < 16; nt++) {
    const int n0 = nt * 64;

    // mask loads for this tile's PV (issued early, consumed late)
    f32x4 mreg[4];
    #pragma unroll
    for (int ks = 0; ks < 2; ks++)
      #pragma unroll
      for (int h = 0; h < 2; h++)
        mreg[ks * 2 + h] = *(const f32x4*)(mrow + n0 + ks * 32 + h * 4);

    // S = q k^T
    f32x4 sacc[4];
    #pragma unroll
    for (int nsi = 0; nsi < 4; nsi++) {
      sacc[nsi] = (f32x4){0,0,0,0};
      const unsigned short* kp = kb + (size_t)(n0 + nsi * 16) * 128;
      #pragma unroll
      for (int ks = 0; ks < 4; ks++) {
        bf16x8 kf = *(const bf16x8*)(kp + ks * 32);
        sacc[nsi] = __builtin_amdgcn_mfma_f32_16x16x32_bf16(qf[ks], kf, sacc[nsi], 0, 0, 0);
      }
    }

    // P1 = e^t -> wave-private swizzled LDS (row=l4*4+r, col=nsi*16+l15)
    #pragma unroll
    for (int nsi = 0; nsi < 4; nsi++)
      #pragma unroll
      for (int r = 0; r < 4; r++) {
        float e = fast_exp2(sacc[nsi][r] * kSc);
        lsum[r] += e;
        const int row = l4 * 4 + r;
        const int u2 = (nsi * 2 + (l15 >> 3)) ^ (row & 7);
        pb[row * 64 + u2 * 8 + l7] = f2bf(e);
      }

    // A-frags: a1 from pbuf (swizzled read), a2 from mask regs
    bf16x8 a1[2], a2[2];
    #pragma unroll
    for (int ks = 0; ks < 2; ks++) {
      const int u2 = (ks * 4 + l4) ^ l7;
      a1[ks] = *(const bf16x8*)&pb[l15 * 64 + u2 * 8];
      bf16x8 t;
      #pragma unroll
      for (int j = 0; j < 4; j++) {
        t[j]     = (short)f2bf(mreg[ks * 2][j]);
        t[4 + j] = (short)f2bf(mreg[ks * 2 + 1][j]);
      }
      a2[ks] = t;
    }

    // PV: shared V frags, two accumulators
    __builtin_amdgcn_s_setprio(1);
    #pragma unroll
    for (int d = 0; d < 8; d++) {
      const unsigned short* vp = vb + (size_t)(d * 16) * 4096 + n0;
      bf16x8 vf0 = *(const bf16x8*)(vp);
      bf16x8 vf1 = *(const bf16x8*)(vp + 32);
      acc2[d] = __builtin_amdgcn_mfma_f32_16x16x32_bf16(a2[0], vf0, acc2[d], 0, 0, 0);
      acc2[d] = __builtin_amdgcn_mfma_f32_16x16x32_bf16(a2[1], vf1, acc2[d], 0, 0, 0);
      acc1[d] = __builtin_amdgcn_mfma_f32_16x16x32_bf16(a1[0], vf0, acc1[d], 0, 0, 0);
      acc1[d] = __builtin_amdgcn_mfma_f32_16x16x32_bf16(a1[1], vf1, acc1[d], 0, 0, 0);
    }
    __builtin_amdgcn_s_setprio(0);
  }

  // row-sums over this n-range: reduce across the 16 lanes of each row group
  #pragma unroll
  for (int r = 0; r < 4; r++) {
    float s = lsum[r];
    s += __shfl_xor(s, 1); s += __shfl_xor(s, 2);
    s += __shfl_xor(s, 4); s += __shfl_xor(s, 8);
    lsum[r] = s;
  }
  if (l15 == 0)
    #pragma unroll
    for (int r = 0; r < 4; r++)
      rsumws[(size_t)(ns * 4 + b) * 4096 + m0 + w * 16 + l4 * 4 + r] = lsum[r];

  // partial outputs: pack (bf16(acc1), bf16(acc2)) into u32
  unsigned int* pp = part + ((size_t)(ns * 4 + b) * 4096 + m0 + w * 16) * 128;
  #pragma unroll
  for (int d = 0; d < 8; d++)
    #pragma unroll
    for (int r = 0; r < 4; r++) {
      unsigned int u = ((unsigned int)f2bf(acc2[d][r]) << 16) | (unsigned int)f2bf(acc1[d][r]);
      pp[(size_t)(l4 * 4 + r) * 128 + d * 16 + l15] = u;
    }
}

// ---------------- kernel 3: combine n-split partials ------------------------
__global__ __launch_bounds__(256) void combine_kernel(
    const unsigned int* __restrict__ part, const float* __restrict__ rsumws,
    float* __restrict__ out)
{
  const size_t i = (size_t)blockIdx.x * 256 + threadIdx.x;   // 2M outputs
  const int row = (int)(i >> 7);                              // b*4096 + m
  float s1 = 0.f, s2 = 0.f, rs = 0.f;
  #pragma unroll
  for (int ns = 0; ns < 4; ns++) {
    unsigned int u = part[(size_t)ns * 2097152 + i];
    s1 += __uint_as_float(u << 16);
    s2 += __uint_as_float(u & 0xFFFF0000u);
    rs += rsumws[ns * 16384 + row];
  }
  out[i] = s1 * (1.0f / rs) + s2;
}

extern "C" void kernel_launch(void* const* d_in, const int* in_sizes, int n_in,
                              void* d_out, int out_size, void* d_ws, size_t ws_size,
                              hipStream_t stream) {
  const float* x    = (const float*)d_in[0];
  const float* cond = (const float*)d_in[1];
  const float* mask = (const float*)d_in[2];
  const float* Wq   = (const float*)d_in[3];
  const float* Wkv  = (const float*)d_in[4];

  unsigned short* qws = (unsigned short*)d_ws;
  unsigned short* kws = qws + (size_t)4 * 4096 * 128;
  unsigned short* vT  = kws + (size_t)4 * 4096 * 128;
  unsigned short* wqb = vT  + (size_t)4 * 128 * 4096;
  unsigned short* wkb = wqb + 128 * 128;
  unsigned int*  part = (unsigned int*)(wkb + 128 * 128);
  float*         rsum = (float*)(part + (size_t)4 * 4 * 4096 * 128);

  hipLaunchKernelGGL(wcvt_kernel, dim3(8), dim3(256), 0, stream, Wq, Wkv, wqb, wkb);
  hipLaunchKernelGGL(proj_kernel, dim3(768), dim3(256), 0, stream,
                     x, cond, wqb, wkb, qws, kws, vT);
  hipLaunchKernelGGL(attn_kernel, dim3(1024), dim3(256), 0, stream,
                     qws, kws, vT, mask, part, rsum);
  hipLaunchKernelGGL(combine_kernel, dim3(8192), dim3(256), 0, stream,
                     part, rsum, (float*)d_out);
}